// Round 6
// baseline (814.178 us; speedup 1.0000x reference)
//
#include <hip/hip_runtime.h>
#include <float.h>
#include <math.h>

#define NN 8192
#define DH 256
#define KNN 10
#define TSTEPS 10
#define EPSC 0.1f
#define CTILE 1024          // candidates staged in LDS per tile
#define QPB 16              // queries per block (16 waves of 64)

typedef short s8v __attribute__((ext_vector_type(8)));
typedef float f4v __attribute__((ext_vector_type(4)));

__device__ __forceinline__ float bf2f(unsigned short u) {
    union { unsigned u; float f; } c; c.u = ((unsigned)u) << 16; return c.f;
}
__device__ __forceinline__ unsigned short f2bf(float f) {
    union { float f; unsigned u; } c; c.f = f;
    unsigned r = c.u + 0x7FFF + ((c.u >> 16) & 1);
    return (unsigned short)(r >> 16);
}

// ---------------- conv_ws [3][256][256] (k,n) -> bf16 Wt [3][n][k] ------------
__global__ void prep_wt(const float* __restrict__ W, unsigned short* __restrict__ Wt) {
    int e = blockIdx.x * 256 + threadIdx.x;
    int g = e >> 16; int rem = e & 65535;
    int n = rem >> 8; int k = rem & 255;
    Wt[e] = f2bf(W[g * 65536 + k * 256 + n]);
}

// ---------------- pos4[j] = {x, y, z, |p|^2} ----------------------------------
__global__ void prep_pos(const float* __restrict__ pos, float4* __restrict__ pos4) {
    int j = blockIdx.x * 256 + threadIdx.x;
    float x = pos[j * 3], y = pos[j * 3 + 1], z = pos[j * 3 + 2];
    float4 v; v.x = x; v.y = y; v.z = z; v.w = x * x + y * y + z * z;
    pos4[j] = v;
}

// ---------------- kNN: 1 wave/query, 16 queries/block, DPP-insert pops --------
// Distributed top-10: rank r lives in LANE r, sorted ascending (R2's verified
// semantics). A pop is readlane-broadcast + v_mov_dpp row_shr:1 shift (ranks
// 0..9 all sit in one 16-lane DPP row) + 2 cmp + 4 cndmask — ~8 short-latency
// VALU ops, no DS ops (R2's wall) and no 50-op SALU network (R4's wall: one
// scalar unit per CU => ~86us aggregate floor; measured 123us).
// Candidates arrive in ascending j; strict '<' keeps lower index on ties.
__launch_bounds__(1024)
__global__ void knn_wave(const float* __restrict__ pos, const float4* __restrict__ pos4,
                         int* __restrict__ nbr) {
    __shared__ float4 cand[CTILE];
    int tid = threadIdx.x;
    int wv = tid >> 6, lane = tid & 63;
    int i = blockIdx.x * QPB + wv;               // query for this wave
    float xi = pos[i * 3], yi = pos[i * 3 + 1], zi = pos[i * 3 + 2];
    float sqi = xi * xi + yi * yi + zi * zi;
    int igrp = i & ~63;                          // the only 64-group containing i

    float b  = FLT_MAX;                          // rank 'lane' distance
    int   ib = -1;                               // rank 'lane' index
    float thr = FLT_MAX;                         // 10th best (b at lane 9)

    for (int tile = 0; tile < NN / CTILE; ++tile) {
        __syncthreads();
        cand[tid] = pos4[tile * CTILE + tid];    // 1024 threads, 1 float4 each
        __syncthreads();
#pragma unroll 4
        for (int u = 0; u < CTILE / 64; ++u) {
            int jgrp = tile * CTILE + u * 64;
            float4 c = cand[u * 64 + lane];
            int j = jgrp + lane;
            float m = c.x * xi + c.y * yi + c.z * zi;
            float d = (sqi + c.w) - 2.0f * m;
            if (jgrp == igrp) {                  // wave-uniform branch
                if (j == i) d = FLT_MAX;         // self-exclusion, one batch only
            }
            unsigned long long mask = __ballot(d < thr);
            while (mask) {
                int l = __ffsll((unsigned long long)mask) - 1;
                mask &= mask - 1;
                float dc = __int_as_float(__builtin_amdgcn_readlane(__float_as_int(d), l));
                if (dc < thr) {                  // recheck vs updated threshold
                    int jc = __builtin_amdgcn_readlane(j, l);
                    // shift-down neighbors via DPP row_shr:1 (lane r <- r-1)
                    float bp = __int_as_float(__builtin_amdgcn_update_dpp(
                        0, __float_as_int(b), 0x111, 0xF, 0xF, true));
                    int ip = __builtin_amdgcn_update_dpp(0, ib, 0x111, 0xF, 0xF, true);
                    bool c0 = dc < b;                    // insert at/below my rank
                    bool cp = (lane != 0) && (dc < bp);  // insert strictly below
                    b  = c0 ? (cp ? bp : dc) : b;
                    ib = c0 ? (cp ? ip : jc) : ib;
                    thr = __int_as_float(__builtin_amdgcn_readlane(__float_as_int(b), 9));
                }
            }
        }
    }
    if (lane < KNN) nbr[i * KNN + lane] = ib;    // rank r already in lane r
}

// ---------------- h = lm@emb_w + emb_b ; x = h@rw + rb ------------------------
__global__ void emb_kernel(const float* __restrict__ lm, const float* __restrict__ ew,
                           const float* __restrict__ eb, const float* __restrict__ rw,
                           const float* __restrict__ rb,
                           float* __restrict__ hdo, unsigned short* __restrict__ hbf,
                           float* __restrict__ xout) {
    __shared__ float s0[4], s1[4], s2[4];
    int i = blockIdx.x, d = threadIdx.x;
    float a0 = lm[i * 3], a1 = lm[i * 3 + 1], a2 = lm[i * 3 + 2];
    float h = eb[d] + a0 * ew[d] + a1 * ew[256 + d] + a2 * ew[512 + d];
    hdo[i * 256 + d] = h;
    hbf[i * 256 + d] = f2bf(h);
    float p0 = h * rw[d * 3], p1 = h * rw[d * 3 + 1], p2 = h * rw[d * 3 + 2];
    for (int off = 32; off; off >>= 1) {
        p0 += __shfl_down(p0, off, 64);
        p1 += __shfl_down(p1, off, 64);
        p2 += __shfl_down(p2, off, 64);
    }
    int lane = d & 63, wid = d >> 6;
    if (lane == 0) { s0[wid] = p0; s1[wid] = p1; s2[wid] = p2; }
    __syncthreads();
    if (d == 0) {
        xout[i * 3 + 0] = s0[0] + s0[1] + s0[2] + s0[3] + rb[0];
        xout[i * 3 + 1] = s1[0] + s1[1] + s1[2] + s1[3] + rb[1];
        xout[i * 3 + 2] = s2[0] + s2[1] + s2[2] + s2[3] + rb[2];
    }
}

// ---------------- hop-1: x1[i] = 0.1 * sum_{j in nbr(i)} hbf[j] ---------------
__global__ void agg_kernel(const unsigned short* __restrict__ src,
                           unsigned short* __restrict__ dst,
                           const int* __restrict__ nbr) {
    int tid = threadIdx.x;
    int wid = tid >> 6, lane = tid & 63;
    int node = blockIdx.x * 4 + wid;
    int d0 = lane * 4;
    float a0 = 0.f, a1 = 0.f, a2 = 0.f, a3 = 0.f;
    const int* nb = nbr + node * KNN;
    for (int q = 0; q < KNN; q++) {
        int j = nb[q];
        uint2 v = *(const uint2*)(src + j * 256 + d0);
        a0 += bf2f((unsigned short)(v.x & 0xffff));
        a1 += bf2f((unsigned short)(v.x >> 16));
        a2 += bf2f((unsigned short)(v.y & 0xffff));
        a3 += bf2f((unsigned short)(v.y >> 16));
    }
    uint2 o;
    o.x = (unsigned)f2bf(a0 * 0.1f) | ((unsigned)f2bf(a1 * 0.1f) << 16);
    o.y = (unsigned)f2bf(a2 * 0.1f) | ((unsigned)f2bf(a3 * 0.1f) << 16);
    *(uint2*)(dst + node * 256 + d0) = o;
}

// ------- fused: hop-2 gather + LDS-staged GEMM + Euler + readout --------------
// R4 structure (M16, 256 thr, grid 512, staged B in LDS — known 28us) with T14
// async-STAGE split: chunk kc+1's global loads ISSUE before chunk kc's MFMA,
// ds_write lands after the post-MFMA barrier. Stage latency (~230cyc L2)
// overlaps compute instead of being serially exposed every chunk.
__launch_bounds__(256)
__global__ void gemm_step(unsigned short* hbf,
                          const unsigned short* __restrict__ x1,
                          const int* __restrict__ nbr,
                          const unsigned short* __restrict__ Wt,
                          const float* __restrict__ cb,
                          const float* __restrict__ rw, const float* __restrict__ rb,
                          float* hdo, float* __restrict__ yout, float* yfin) {
    __shared__ __align__(16) short Al[16 * 72];
    __shared__ __align__(16) short Bl[256 * 72];
    __shared__ __align__(16) short X2[16 * 264];
    __shared__ float rwl[768];
    __shared__ float cbl[256];
    __shared__ float yred[4][4][4][3];     // [wave][quad][r][xyz]

    int tid = threadIdx.x;
    int m0 = blockIdx.x * 16;
    for (int idx = tid; idx < 768; idx += 256) rwl[idx] = rw[idx];
    cbl[tid] = cb[tid];

    // ---- fused hop-2 aggregation: X2[row][:] = bf16(0.1 * sum x1[nbr[row]]) ----
    {
        int row = tid >> 4, cg = tid & 15;          // 16 threads per row, 16 dims each
        const int* nb = nbr + (m0 + row) * KNN;
        float a[16];
#pragma unroll
        for (int e = 0; e < 16; e++) a[e] = 0.f;
        for (int q = 0; q < KNN; q++) {
            int j = nb[q];
            const uint4* p = (const uint4*)(x1 + j * 256 + cg * 16);
#pragma unroll
            for (int u = 0; u < 2; u++) {
                uint4 v = p[u];
                a[u*8+0] += bf2f((unsigned short)(v.x & 0xffff));
                a[u*8+1] += bf2f((unsigned short)(v.x >> 16));
                a[u*8+2] += bf2f((unsigned short)(v.y & 0xffff));
                a[u*8+3] += bf2f((unsigned short)(v.y >> 16));
                a[u*8+4] += bf2f((unsigned short)(v.z & 0xffff));
                a[u*8+5] += bf2f((unsigned short)(v.z >> 16));
                a[u*8+6] += bf2f((unsigned short)(v.w & 0xffff));
                a[u*8+7] += bf2f((unsigned short)(v.w >> 16));
            }
        }
        unsigned short* xp = (unsigned short*)&X2[row * 264 + cg * 16];
#pragma unroll
        for (int u = 0; u < 2; u++) {
            uint4 o;
            o.x = (unsigned)f2bf(a[u*8+0]*0.1f) | ((unsigned)f2bf(a[u*8+1]*0.1f) << 16);
            o.y = (unsigned)f2bf(a[u*8+2]*0.1f) | ((unsigned)f2bf(a[u*8+3]*0.1f) << 16);
            o.z = (unsigned)f2bf(a[u*8+4]*0.1f) | ((unsigned)f2bf(a[u*8+5]*0.1f) << 16);
            o.w = (unsigned)f2bf(a[u*8+6]*0.1f) | ((unsigned)f2bf(a[u*8+7]*0.1f) << 16);
            *(uint4*)(xp + u * 8) = o;
        }
    }

    f4v acc[4];
    for (int f = 0; f < 4; f++) acc[f] = (f4v){0.f, 0.f, 0.f, 0.f};

    int w = tid >> 6, lane = tid & 63;
    int quad = lane >> 4, l15 = lane & 15;
    int c8 = (tid & 7) * 8, rbase = tid >> 3;     // B-stage coords

    uint4 breg[8]; uint4 areg;

    // ---- prologue: stage chunk 0 -------------------------------------------
    {
#pragma unroll
        for (int r2 = 0; r2 < 8; r2++)
            breg[r2] = *(const uint4*)(Wt + (r2 * 32 + rbase) * 256 + c8);
        if (tid < 128) {
            int row = tid >> 3, ca = (tid & 7) * 8;
            areg = *(const uint4*)(((const unsigned short*)hbf) + (m0 + row) * 256 + ca);
        }
#pragma unroll
        for (int r2 = 0; r2 < 8; r2++)
            *(uint4*)(&Bl[(r2 * 32 + rbase) * 72 + c8]) = breg[r2];
        if (tid < 128) {
            int row = tid >> 3, ca = (tid & 7) * 8;
            *(uint4*)(&Al[row * 72 + ca]) = areg;
        }
    }
    __syncthreads();      // chunk 0 + X2 visible

    for (int kc = 0; kc < 12; kc++) {
        // ---- issue loads for chunk kc+1 (latency hides under MFMA below) ----
        if (kc + 1 < 12) {
            int kb1 = (kc + 1) * 64;
            const unsigned short* bsrc = Wt + (kb1 >> 8) * 65536;
            int kl = kb1 & 255;
#pragma unroll
            for (int r2 = 0; r2 < 8; r2++)
                breg[r2] = *(const uint4*)(bsrc + (r2 * 32 + rbase) * 256 + kl + c8);
            if (kc + 1 < 8 && tid < 128) {
                const unsigned short* asrc = (kb1 < 256) ? (const unsigned short*)hbf : x1;
                int row = tid >> 3, ca = (tid & 7) * 8;
                areg = *(const uint4*)(asrc + (m0 + row) * 256 + (kb1 & 255) + ca);
            }
        }
        // ---- MFMA on chunk kc ----------------------------------------------
        int klocal = (kc * 64) & 255;
        for (int ks = 0; ks < 2; ks++) {
            s8v a;
            if (kc < 8)
                a = *(const s8v*)(&Al[l15 * 72 + ks * 32 + quad * 8]);
            else
                a = *(const s8v*)(&X2[l15 * 264 + klocal + ks * 32 + quad * 8]);
            for (int f = 0; f < 4; f++) {
                int n = w * 64 + f * 16 + l15;
                s8v b = *(const s8v*)(&Bl[n * 72 + ks * 32 + quad * 8]);
                acc[f] = __builtin_amdgcn_mfma_f32_16x16x32_bf16(a, b, acc[f], 0, 0, 0);
            }
        }
        __syncthreads();   // everyone done reading chunk kc
        // ---- write chunk kc+1 into LDS -------------------------------------
        if (kc + 1 < 12) {
#pragma unroll
            for (int r2 = 0; r2 < 8; r2++)
                *(uint4*)(&Bl[(r2 * 32 + rbase) * 72 + c8]) = breg[r2];
            if (kc + 1 < 8 && tid < 128) {
                int row = tid >> 3, ca = (tid & 7) * 8;
                *(uint4*)(&Al[row * 72 + ca]) = areg;
            }
            __syncthreads();   // chunk kc+1 visible
        }
    }

    float py[4][3] = {};
    for (int f = 0; f < 4; f++) {
        int col = w * 64 + f * 16 + l15;
        float cbv = cbl[col];
        float rw0 = rwl[col * 3], rw1 = rwl[col * 3 + 1], rw2 = rwl[col * 3 + 2];
        for (int r = 0; r < 4; r++) {
            int grow = m0 + quad * 4 + r;
            float cval = acc[f][r] + cbv;
            float hn = hdo[grow * 256 + col] + EPSC * tanhf(cval);
            hdo[grow * 256 + col] = hn;
            hbf[grow * 256 + col] = f2bf(hn);
            py[r][0] += hn * rw0; py[r][1] += hn * rw1; py[r][2] += hn * rw2;
        }
    }
    for (int off = 1; off < 16; off <<= 1)
        for (int r = 0; r < 4; r++)
            for (int j = 0; j < 3; j++)
                py[r][j] += __shfl_xor(py[r][j], off, 64);
    if (l15 == 0)
        for (int r = 0; r < 4; r++)
            for (int j = 0; j < 3; j++)
                yred[w][quad][r][j] = py[r][j];
    __syncthreads();
    if (w == 0 && l15 == 0) {
        for (int r = 0; r < 4; r++) {
            int grow = m0 + quad * 4 + r;
            for (int j = 0; j < 3; j++) {
                float yv = yred[0][quad][r][j] + yred[1][quad][r][j]
                         + yred[2][quad][r][j] + yred[3][quad][r][j] + rb[j];
                yout[grow * 3 + j] = yv;
                if (yfin) yfin[grow * 3 + j] = yv;
            }
        }
    }
}

extern "C" void kernel_launch(void* const* d_in, const int* in_sizes, int n_in,
                              void* d_out, int out_size, void* d_ws, size_t ws_size,
                              hipStream_t stream) {
    const float* lm = (const float*)d_in[0];
    const float* ew = (const float*)d_in[1];
    const float* eb = (const float*)d_in[2];
    const float* rw = (const float*)d_in[3];
    const float* rb = (const float*)d_in[4];
    const float* cw = (const float*)d_in[5];
    const float* cb = (const float*)d_in[6];

    float* out = (float*)d_out;
    float* y_out = out;
    float* h_out = out + 24576;
    float* x_out = out + 24576 + 2097152;
    float* lp_out = x_out + 24576;

    char* ws = (char*)d_ws;
    int* nbr = (int*)ws;                       ws += NN * KNN * sizeof(int);
    float4* pos4 = (float4*)ws;                ws += NN * sizeof(float4);
    char* uni = ws;
    unsigned short* hbf = (unsigned short*)uni;
    unsigned short* x1  = hbf + NN * DH;
    unsigned short* Wt  = x1 + NN * DH;

    prep_pos<<<NN / 256, 256, 0, stream>>>(lm, pos4);
    knn_wave<<<NN / QPB, 1024, 0, stream>>>(lm, pos4, nbr);
    prep_wt<<<768, 256, 0, stream>>>(cw, Wt);
    emb_kernel<<<NN, 256, 0, stream>>>(lm, ew, eb, rw, rb, h_out, hbf, x_out);
    for (int t = 0; t < TSTEPS; t++) {
        agg_kernel<<<NN / 4, 256, 0, stream>>>(hbf, x1, nbr);
        gemm_step<<<NN / 16, 256, 0, stream>>>(hbf, x1, nbr, Wt, cb, rw, rb, h_out,
                                               lp_out + t * 24576,
                                               (t == TSTEPS - 1) ? y_out : nullptr);
    }
}

// Round 7
// 435.373 us; speedup vs baseline: 1.8701x; 1.8701x over previous
//
#include <hip/hip_runtime.h>
#include <float.h>
#include <math.h>

#define NN 8192
#define DH 256
#define KNN 10
#define TSTEPS 10
#define EPSC 0.1f
#define CTILE 1024          // candidates staged in LDS per tile
#define QPB 16              // queries per block (16 waves of 64)

typedef short s8v __attribute__((ext_vector_type(8)));
typedef float f4v __attribute__((ext_vector_type(4)));

__device__ __forceinline__ float bf2f(unsigned short u) {
    union { unsigned u; float f; } c; c.u = ((unsigned)u) << 16; return c.f;
}
__device__ __forceinline__ unsigned short f2bf(float f) {
    union { float f; unsigned u; } c; c.f = f;
    unsigned r = c.u + 0x7FFF + ((c.u >> 16) & 1);
    return (unsigned short)(r >> 16);
}

// ---------------- conv_ws [3][256][256] (k,n) -> bf16 Wt [3][n][k] ------------
__global__ void prep_wt(const float* __restrict__ W, unsigned short* __restrict__ Wt) {
    int e = blockIdx.x * 256 + threadIdx.x;
    int g = e >> 16; int rem = e & 65535;
    int n = rem >> 8; int k = rem & 255;
    Wt[e] = f2bf(W[g * 65536 + k * 256 + n]);
}

// ---------------- pos4[j] = {x, y, z, |p|^2} ----------------------------------
__global__ void prep_pos(const float* __restrict__ pos, float4* __restrict__ pos4) {
    int j = blockIdx.x * 256 + threadIdx.x;
    float x = pos[j * 3], y = pos[j * 3 + 1], z = pos[j * 3 + 2];
    float4 v; v.x = x; v.y = y; v.z = z; v.w = x * x + y * y + z * z;
    pos4[j] = v;
}

// ---------------- kNN: 1 wave/query, 16 queries/block, DPP-insert pops --------
// Distributed top-10: rank r lives in LANE r, sorted ascending. A pop is
// readlane-broadcast + v_mov_dpp row_shr:1 shift (ranks 0..9 sit in one
// 16-lane DPP row) + 2 cmp + 4 cndmask — ~8 short-latency VALU ops, no DS ops
// (R2's wall) and no 50-op SALU network (R4's wall). Measured ~40us (R6).
// Candidates arrive in ascending j; strict '<' keeps lower index on ties.
__launch_bounds__(1024)
__global__ void knn_wave(const float* __restrict__ pos, const float4* __restrict__ pos4,
                         int* __restrict__ nbr) {
    __shared__ float4 cand[CTILE];
    int tid = threadIdx.x;
    int wv = tid >> 6, lane = tid & 63;
    int i = blockIdx.x * QPB + wv;               // query for this wave
    float xi = pos[i * 3], yi = pos[i * 3 + 1], zi = pos[i * 3 + 2];
    float sqi = xi * xi + yi * yi + zi * zi;
    int igrp = i & ~63;                          // the only 64-group containing i

    float b  = FLT_MAX;                          // rank 'lane' distance
    int   ib = -1;                               // rank 'lane' index
    float thr = FLT_MAX;                         // 10th best (b at lane 9)

    for (int tile = 0; tile < NN / CTILE; ++tile) {
        __syncthreads();
        cand[tid] = pos4[tile * CTILE + tid];    // 1024 threads, 1 float4 each
        __syncthreads();
#pragma unroll 4
        for (int u = 0; u < CTILE / 64; ++u) {
            int jgrp = tile * CTILE + u * 64;
            float4 c = cand[u * 64 + lane];
            int j = jgrp + lane;
            float m = c.x * xi + c.y * yi + c.z * zi;
            float d = (sqi + c.w) - 2.0f * m;
            if (jgrp == igrp) {                  // wave-uniform branch
                if (j == i) d = FLT_MAX;         // self-exclusion, one batch only
            }
            unsigned long long mask = __ballot(d < thr);
            while (mask) {
                int l = __ffsll((unsigned long long)mask) - 1;
                mask &= mask - 1;
                float dc = __int_as_float(__builtin_amdgcn_readlane(__float_as_int(d), l));
                if (dc < thr) {                  // recheck vs updated threshold
                    int jc = __builtin_amdgcn_readlane(j, l);
                    // shift-down neighbors via DPP row_shr:1 (lane r <- r-1)
                    float bp = __int_as_float(__builtin_amdgcn_update_dpp(
                        0, __float_as_int(b), 0x111, 0xF, 0xF, true));
                    int ip = __builtin_amdgcn_update_dpp(0, ib, 0x111, 0xF, 0xF, true);
                    bool c0 = dc < b;                    // insert at/below my rank
                    bool cp = (lane != 0) && (dc < bp);  // insert strictly below
                    b  = c0 ? (cp ? bp : dc) : b;
                    ib = c0 ? (cp ? ip : jc) : ib;
                    thr = __int_as_float(__builtin_amdgcn_readlane(__float_as_int(b), 9));
                }
            }
        }
    }
    if (lane < KNN) nbr[i * KNN + lane] = ib;    // rank r already in lane r
}

// ---------------- h = lm@emb_w + emb_b ; x = h@rw + rb ------------------------
__global__ void emb_kernel(const float* __restrict__ lm, const float* __restrict__ ew,
                           const float* __restrict__ eb, const float* __restrict__ rw,
                           const float* __restrict__ rb,
                           float* __restrict__ hdo, unsigned short* __restrict__ hbf,
                           float* __restrict__ xout) {
    __shared__ float s0[4], s1[4], s2[4];
    int i = blockIdx.x, d = threadIdx.x;
    float a0 = lm[i * 3], a1 = lm[i * 3 + 1], a2 = lm[i * 3 + 2];
    float h = eb[d] + a0 * ew[d] + a1 * ew[256 + d] + a2 * ew[512 + d];
    hdo[i * 256 + d] = h;
    hbf[i * 256 + d] = f2bf(h);
    float p0 = h * rw[d * 3], p1 = h * rw[d * 3 + 1], p2 = h * rw[d * 3 + 2];
    for (int off = 32; off; off >>= 1) {
        p0 += __shfl_down(p0, off, 64);
        p1 += __shfl_down(p1, off, 64);
        p2 += __shfl_down(p2, off, 64);
    }
    int lane = d & 63, wid = d >> 6;
    if (lane == 0) { s0[wid] = p0; s1[wid] = p1; s2[wid] = p2; }
    __syncthreads();
    if (d == 0) {
        xout[i * 3 + 0] = s0[0] + s0[1] + s0[2] + s0[3] + rb[0];
        xout[i * 3 + 1] = s1[0] + s1[1] + s1[2] + s1[3] + rb[1];
        xout[i * 3 + 2] = s2[0] + s2[1] + s2[2] + s2[3] + rb[2];
    }
}

// ---------------- hop-1: x1[i] = 0.1 * sum_{j in nbr(i)} hbf[j] ---------------
__global__ void agg_kernel(const unsigned short* __restrict__ src,
                           unsigned short* __restrict__ dst,
                           const int* __restrict__ nbr) {
    int tid = threadIdx.x;
    int wid = tid >> 6, lane = tid & 63;
    int node = blockIdx.x * 4 + wid;
    int d0 = lane * 4;
    float a0 = 0.f, a1 = 0.f, a2 = 0.f, a3 = 0.f;
    const int* nb = nbr + node * KNN;
    for (int q = 0; q < KNN; q++) {
        int j = nb[q];
        uint2 v = *(const uint2*)(src + j * 256 + d0);
        a0 += bf2f((unsigned short)(v.x & 0xffff));
        a1 += bf2f((unsigned short)(v.x >> 16));
        a2 += bf2f((unsigned short)(v.y & 0xffff));
        a3 += bf2f((unsigned short)(v.y >> 16));
    }
    uint2 o;
    o.x = (unsigned)f2bf(a0 * 0.1f) | ((unsigned)f2bf(a1 * 0.1f) << 16);
    o.y = (unsigned)f2bf(a2 * 0.1f) | ((unsigned)f2bf(a3 * 0.1f) << 16);
    *(uint2*)(dst + node * 256 + d0) = o;
}

// ------- fused: hop-2 gather + GEMM + Euler + readout. M-tile 16, grid 512 ----
// R3/R4 known-good structure (~28us/dispatch). T14 register double-buffer
// attempt (R6) spilled breg[] to scratch: WRITE_SIZE 12->65MB, occupancy 17%.
// Reverted verbatim; do not hold staging registers across barriers here.
__launch_bounds__(256)
__global__ void gemm_step(unsigned short* hbf,
                          const unsigned short* __restrict__ x1,
                          const int* __restrict__ nbr,
                          const unsigned short* __restrict__ Wt,
                          const float* __restrict__ cb,
                          const float* __restrict__ rw, const float* __restrict__ rb,
                          float* hdo, float* __restrict__ yout, float* yfin) {
    __shared__ __align__(16) short Al[16 * 72];
    __shared__ __align__(16) short Bl[256 * 72];
    __shared__ __align__(16) short X2[16 * 264];
    __shared__ float rwl[768];
    __shared__ float cbl[256];
    __shared__ float yred[4][4][4][3];     // [wave][quad][r][xyz]

    int tid = threadIdx.x;
    int m0 = blockIdx.x * 16;
    for (int idx = tid; idx < 768; idx += 256) rwl[idx] = rw[idx];
    cbl[tid] = cb[tid];

    // ---- fused hop-2 aggregation: X2[row][:] = bf16(0.1 * sum x1[nbr[row]]) ----
    {
        int row = tid >> 4, cg = tid & 15;          // 16 threads per row, 16 dims each
        const int* nb = nbr + (m0 + row) * KNN;
        float a[16];
#pragma unroll
        for (int e = 0; e < 16; e++) a[e] = 0.f;
        for (int q = 0; q < KNN; q++) {
            int j = nb[q];
            const uint4* p = (const uint4*)(x1 + j * 256 + cg * 16);
#pragma unroll
            for (int u = 0; u < 2; u++) {
                uint4 v = p[u];
                a[u*8+0] += bf2f((unsigned short)(v.x & 0xffff));
                a[u*8+1] += bf2f((unsigned short)(v.x >> 16));
                a[u*8+2] += bf2f((unsigned short)(v.y & 0xffff));
                a[u*8+3] += bf2f((unsigned short)(v.y >> 16));
                a[u*8+4] += bf2f((unsigned short)(v.z & 0xffff));
                a[u*8+5] += bf2f((unsigned short)(v.z >> 16));
                a[u*8+6] += bf2f((unsigned short)(v.w & 0xffff));
                a[u*8+7] += bf2f((unsigned short)(v.w >> 16));
            }
        }
        unsigned short* xp = (unsigned short*)&X2[row * 264 + cg * 16];
#pragma unroll
        for (int u = 0; u < 2; u++) {
            uint4 o;
            o.x = (unsigned)f2bf(a[u*8+0]*0.1f) | ((unsigned)f2bf(a[u*8+1]*0.1f) << 16);
            o.y = (unsigned)f2bf(a[u*8+2]*0.1f) | ((unsigned)f2bf(a[u*8+3]*0.1f) << 16);
            o.z = (unsigned)f2bf(a[u*8+4]*0.1f) | ((unsigned)f2bf(a[u*8+5]*0.1f) << 16);
            o.w = (unsigned)f2bf(a[u*8+6]*0.1f) | ((unsigned)f2bf(a[u*8+7]*0.1f) << 16);
            *(uint4*)(xp + u * 8) = o;
        }
    }

    f4v acc[4];
    for (int f = 0; f < 4; f++) acc[f] = (f4v){0.f, 0.f, 0.f, 0.f};

    int w = tid >> 6, lane = tid & 63;
    int quad = lane >> 4, l15 = lane & 15;

    for (int kc = 0; kc < 12; kc++) {
        int kb = kc * 64;
        int klocal = kb & 255;
        if (kc < 8 && tid < 128) {
            const unsigned short* asrc = (kb < 256) ? (const unsigned short*)hbf : x1;
            int row = tid >> 3, c8 = (tid & 7) * 8;
            uint4 v = *(const uint4*)(asrc + (m0 + row) * 256 + klocal + c8);
            *(uint4*)(&Al[row * 72 + c8]) = v;
        }
        {
            const unsigned short* bsrc = Wt + (kb >> 8) * 65536;
            int c8 = (tid & 7) * 8, rbase = tid >> 3;
            for (int r2 = 0; r2 < 8; r2++) {
                int n = r2 * 32 + rbase;
                uint4 v = *(const uint4*)(bsrc + n * 256 + klocal + c8);
                *(uint4*)(&Bl[n * 72 + c8]) = v;
            }
        }
        __syncthreads();
        for (int ks = 0; ks < 2; ks++) {
            s8v a;
            if (kc < 8)
                a = *(const s8v*)(&Al[l15 * 72 + ks * 32 + quad * 8]);
            else
                a = *(const s8v*)(&X2[l15 * 264 + klocal + ks * 32 + quad * 8]);
            for (int f = 0; f < 4; f++) {
                int n = w * 64 + f * 16 + l15;
                s8v b = *(const s8v*)(&Bl[n * 72 + ks * 32 + quad * 8]);
                acc[f] = __builtin_amdgcn_mfma_f32_16x16x32_bf16(a, b, acc[f], 0, 0, 0);
            }
        }
        __syncthreads();
    }

    float py[4][3] = {};
    for (int f = 0; f < 4; f++) {
        int col = w * 64 + f * 16 + l15;
        float cbv = cbl[col];
        float rw0 = rwl[col * 3], rw1 = rwl[col * 3 + 1], rw2 = rwl[col * 3 + 2];
        for (int r = 0; r < 4; r++) {
            int grow = m0 + quad * 4 + r;
            float cval = acc[f][r] + cbv;
            float hn = hdo[grow * 256 + col] + EPSC * tanhf(cval);
            hdo[grow * 256 + col] = hn;
            hbf[grow * 256 + col] = f2bf(hn);
            py[r][0] += hn * rw0; py[r][1] += hn * rw1; py[r][2] += hn * rw2;
        }
    }
    for (int off = 1; off < 16; off <<= 1)
        for (int r = 0; r < 4; r++)
            for (int j = 0; j < 3; j++)
                py[r][j] += __shfl_xor(py[r][j], off, 64);
    if (l15 == 0)
        for (int r = 0; r < 4; r++)
            for (int j = 0; j < 3; j++)
                yred[w][quad][r][j] = py[r][j];
    __syncthreads();
    if (w == 0 && l15 == 0) {
        for (int r = 0; r < 4; r++) {
            int grow = m0 + quad * 4 + r;
            for (int j = 0; j < 3; j++) {
                float yv = yred[0][quad][r][j] + yred[1][quad][r][j]
                         + yred[2][quad][r][j] + yred[3][quad][r][j] + rb[j];
                yout[grow * 3 + j] = yv;
                if (yfin) yfin[grow * 3 + j] = yv;
            }
        }
    }
}

extern "C" void kernel_launch(void* const* d_in, const int* in_sizes, int n_in,
                              void* d_out, int out_size, void* d_ws, size_t ws_size,
                              hipStream_t stream) {
    const float* lm = (const float*)d_in[0];
    const float* ew = (const float*)d_in[1];
    const float* eb = (const float*)d_in[2];
    const float* rw = (const float*)d_in[3];
    const float* rb = (const float*)d_in[4];
    const float* cw = (const float*)d_in[5];
    const float* cb = (const float*)d_in[6];

    float* out = (float*)d_out;
    float* y_out = out;
    float* h_out = out + 24576;
    float* x_out = out + 24576 + 2097152;
    float* lp_out = x_out + 24576;

    char* ws = (char*)d_ws;
    int* nbr = (int*)ws;                       ws += NN * KNN * sizeof(int);
    float4* pos4 = (float4*)ws;                ws += NN * sizeof(float4);
    char* uni = ws;
    unsigned short* hbf = (unsigned short*)uni;
    unsigned short* x1  = hbf + NN * DH;
    unsigned short* Wt  = x1 + NN * DH;

    prep_pos<<<NN / 256, 256, 0, stream>>>(lm, pos4);
    knn_wave<<<NN / QPB, 1024, 0, stream>>>(lm, pos4, nbr);
    prep_wt<<<768, 256, 0, stream>>>(cw, Wt);
    emb_kernel<<<NN, 256, 0, stream>>>(lm, ew, eb, rw, rb, h_out, hbf, x_out);
    for (int t = 0; t < TSTEPS; t++) {
        agg_kernel<<<NN / 4, 256, 0, stream>>>(hbf, x1, nbr);
        gemm_step<<<NN / 16, 256, 0, stream>>>(hbf, x1, nbr, Wt, cb, rw, rb, h_out,
                                               lp_out + t * 24576,
                                               (t == TSTEPS - 1) ? y_out : nullptr);
    }
}

// Round 8
// 398.805 us; speedup vs baseline: 2.0415x; 1.0917x over previous
//
#include <hip/hip_runtime.h>
#include <float.h>
#include <math.h>

#define NN 8192
#define DH 256
#define KNN 10
#define TSTEPS 10
#define EPSC 0.1f
#define CTILE 1024          // candidates staged in LDS per tile
#define QPB 16              // queries per block (16 waves of 64)

typedef short s8v __attribute__((ext_vector_type(8)));
typedef float f4v __attribute__((ext_vector_type(4)));

__device__ __forceinline__ float bf2f(unsigned short u) {
    union { unsigned u; float f; } c; c.u = ((unsigned)u) << 16; return c.f;
}
__device__ __forceinline__ unsigned short f2bf(float f) {
    union { float f; unsigned u; } c; c.f = f;
    unsigned r = c.u + 0x7FFF + ((c.u >> 16) & 1);
    return (unsigned short)(r >> 16);
}

// ---------------- conv_ws [3][256][256] (k,n) -> bf16 Wt [3][n][k] ------------
__global__ void prep_wt(const float* __restrict__ W, unsigned short* __restrict__ Wt) {
    int e = blockIdx.x * 256 + threadIdx.x;
    int g = e >> 16; int rem = e & 65535;
    int n = rem >> 8; int k = rem & 255;
    Wt[e] = f2bf(W[g * 65536 + k * 256 + n]);
}

// ---------------- pos4[j] = {x, y, z, |p|^2} ----------------------------------
__global__ void prep_pos(const float* __restrict__ pos, float4* __restrict__ pos4) {
    int j = blockIdx.x * 256 + threadIdx.x;
    float x = pos[j * 3], y = pos[j * 3 + 1], z = pos[j * 3 + 2];
    float4 v; v.x = x; v.y = y; v.z = z; v.w = x * x + y * y + z * z;
    pos4[j] = v;
}

// ---------------- kNN: 1 wave/query, 16 queries/block, DPP-insert pops --------
// Measured 54.7us (R7). Rank r lives in LANE r; pop = readlane + DPP row_shr:1
// + 2 cmp + 4 cndmask. Kept as-is.
__launch_bounds__(1024)
__global__ void knn_wave(const float* __restrict__ pos, const float4* __restrict__ pos4,
                         int* __restrict__ nbr) {
    __shared__ float4 cand[CTILE];
    int tid = threadIdx.x;
    int wv = tid >> 6, lane = tid & 63;
    int i = blockIdx.x * QPB + wv;               // query for this wave
    float xi = pos[i * 3], yi = pos[i * 3 + 1], zi = pos[i * 3 + 2];
    float sqi = xi * xi + yi * yi + zi * zi;
    int igrp = i & ~63;                          // the only 64-group containing i

    float b  = FLT_MAX;                          // rank 'lane' distance
    int   ib = -1;                               // rank 'lane' index
    float thr = FLT_MAX;                         // 10th best (b at lane 9)

    for (int tile = 0; tile < NN / CTILE; ++tile) {
        __syncthreads();
        cand[tid] = pos4[tile * CTILE + tid];    // 1024 threads, 1 float4 each
        __syncthreads();
#pragma unroll 4
        for (int u = 0; u < CTILE / 64; ++u) {
            int jgrp = tile * CTILE + u * 64;
            float4 c = cand[u * 64 + lane];
            int j = jgrp + lane;
            float m = c.x * xi + c.y * yi + c.z * zi;
            float d = (sqi + c.w) - 2.0f * m;
            if (jgrp == igrp) {                  // wave-uniform branch
                if (j == i) d = FLT_MAX;         // self-exclusion, one batch only
            }
            unsigned long long mask = __ballot(d < thr);
            while (mask) {
                int l = __ffsll((unsigned long long)mask) - 1;
                mask &= mask - 1;
                float dc = __int_as_float(__builtin_amdgcn_readlane(__float_as_int(d), l));
                if (dc < thr) {                  // recheck vs updated threshold
                    int jc = __builtin_amdgcn_readlane(j, l);
                    // shift-down neighbors via DPP row_shr:1 (lane r <- r-1)
                    float bp = __int_as_float(__builtin_amdgcn_update_dpp(
                        0, __float_as_int(b), 0x111, 0xF, 0xF, true));
                    int ip = __builtin_amdgcn_update_dpp(0, ib, 0x111, 0xF, 0xF, true);
                    bool c0 = dc < b;                    // insert at/below my rank
                    bool cp = (lane != 0) && (dc < bp);  // insert strictly below
                    b  = c0 ? (cp ? bp : dc) : b;
                    ib = c0 ? (cp ? ip : jc) : ib;
                    thr = __int_as_float(__builtin_amdgcn_readlane(__float_as_int(b), 9));
                }
            }
        }
    }
    if (lane < KNN) nbr[i * KNN + lane] = ib;    // rank r already in lane r
}

// ---------------- h = lm@emb_w + emb_b ; x = h@rw + rb ------------------------
__global__ void emb_kernel(const float* __restrict__ lm, const float* __restrict__ ew,
                           const float* __restrict__ eb, const float* __restrict__ rw,
                           const float* __restrict__ rb,
                           float* __restrict__ hdo, unsigned short* __restrict__ hbf,
                           float* __restrict__ xout) {
    __shared__ float s0[4], s1[4], s2[4];
    int i = blockIdx.x, d = threadIdx.x;
    float a0 = lm[i * 3], a1 = lm[i * 3 + 1], a2 = lm[i * 3 + 2];
    float h = eb[d] + a0 * ew[d] + a1 * ew[256 + d] + a2 * ew[512 + d];
    hdo[i * 256 + d] = h;
    hbf[i * 256 + d] = f2bf(h);
    float p0 = h * rw[d * 3], p1 = h * rw[d * 3 + 1], p2 = h * rw[d * 3 + 2];
    for (int off = 32; off; off >>= 1) {
        p0 += __shfl_down(p0, off, 64);
        p1 += __shfl_down(p1, off, 64);
        p2 += __shfl_down(p2, off, 64);
    }
    int lane = d & 63, wid = d >> 6;
    if (lane == 0) { s0[wid] = p0; s1[wid] = p1; s2[wid] = p2; }
    __syncthreads();
    if (d == 0) {
        xout[i * 3 + 0] = s0[0] + s0[1] + s0[2] + s0[3] + rb[0];
        xout[i * 3 + 1] = s1[0] + s1[1] + s1[2] + s1[3] + rb[1];
        xout[i * 3 + 2] = s2[0] + s2[1] + s2[2] + s2[3] + rb[2];
    }
}

// ---------------- hop-1: x1[i] = 0.1 * sum_{j in nbr(i)} hbf[j] ---------------
__global__ void agg_kernel(const unsigned short* __restrict__ src,
                           unsigned short* __restrict__ dst,
                           const int* __restrict__ nbr) {
    int tid = threadIdx.x;
    int wid = tid >> 6, lane = tid & 63;
    int node = blockIdx.x * 4 + wid;
    int d0 = lane * 4;
    float a0 = 0.f, a1 = 0.f, a2 = 0.f, a3 = 0.f;
    const int* nb = nbr + node * KNN;
    for (int q = 0; q < KNN; q++) {
        int j = nb[q];
        uint2 v = *(const uint2*)(src + j * 256 + d0);
        a0 += bf2f((unsigned short)(v.x & 0xffff));
        a1 += bf2f((unsigned short)(v.x >> 16));
        a2 += bf2f((unsigned short)(v.y & 0xffff));
        a3 += bf2f((unsigned short)(v.y >> 16));
    }
    uint2 o;
    o.x = (unsigned)f2bf(a0 * 0.1f) | ((unsigned)f2bf(a1 * 0.1f) << 16);
    o.y = (unsigned)f2bf(a2 * 0.1f) | ((unsigned)f2bf(a3 * 0.1f) << 16);
    *(uint2*)(dst + node * 256 + d0) = o;
}

// ------- fused: hop-2 gather + GEMM + Euler + readout -------------------------
// M32 x N256, 1024 threads (16 waves, 4/SIMD), grid 256 (1 block/CU).
// vs R4-M16: B(Wt) L2 traffic halves (196->98MB/dispatch); A staged per HOP
// (full 256-K in [32][264]) not per chunk; B double-buffered in LDS (not
// registers - R6 spill lesson): per chunk = {issue next-B loads -> MFMA cur ->
// ds_write next-B -> ONE barrier}. 15 barriers total vs 24, and stage latency
// hides under MFMA. Wave w: rows rt=w>>3 (16), cols (w&7)*32..+32 (acc[2]).
// K order 0..767 ascending per output => bit-identical to R4.
__launch_bounds__(1024)
__global__ void gemm_step(unsigned short* hbf,
                          const unsigned short* __restrict__ x1,
                          const int* __restrict__ nbr,
                          const unsigned short* __restrict__ Wt,
                          const float* __restrict__ cb,
                          const float* __restrict__ rw, const float* __restrict__ rb,
                          float* hdo, float* __restrict__ yout, float* yfin) {
    __shared__ __align__(16) short Al[32 * 264];
    __shared__ __align__(16) short X2[32 * 264];
    __shared__ __align__(16) short Bl[2][256 * 72];
    __shared__ float rwl[768];
    __shared__ float cbl[256];
    __shared__ float yred[16][4][4][3];    // [wave][quad][r][xyz]

    int tid = threadIdx.x;
    int m0 = blockIdx.x * 32;
    if (tid < 768) rwl[tid] = rw[tid];
    if (tid < 256) cbl[tid] = cb[tid];

    int w = tid >> 6, lane = tid & 63;
    int quad = lane >> 4, l15 = lane & 15;
    int rt = w >> 3, cfg = w & 7;

    int arow = tid >> 5, acg = tid & 31;          // A/X2 stage coords (32B rows x 16B)
    int bn = tid >> 2, bk = (tid & 3) * 16;       // B stage: n row, k short-offset {0,16,32,48}

    // ---- hop-2 gather: X2[row][:] = bf16(0.1 * sum x1[nbr[row]]), 32 thr/row --
    {
        const int* nb = nbr + (m0 + arow) * KNN;
        float a[8];
#pragma unroll
        for (int e = 0; e < 8; e++) a[e] = 0.f;
        for (int q = 0; q < KNN; q++) {
            int j = nb[q];
            uint4 v = *(const uint4*)(x1 + j * 256 + acg * 8);
            a[0] += bf2f((unsigned short)(v.x & 0xffff));
            a[1] += bf2f((unsigned short)(v.x >> 16));
            a[2] += bf2f((unsigned short)(v.y & 0xffff));
            a[3] += bf2f((unsigned short)(v.y >> 16));
            a[4] += bf2f((unsigned short)(v.z & 0xffff));
            a[5] += bf2f((unsigned short)(v.z >> 16));
            a[6] += bf2f((unsigned short)(v.w & 0xffff));
            a[7] += bf2f((unsigned short)(v.w >> 16));
        }
        uint4 o;
        o.x = (unsigned)f2bf(a[0]*0.1f) | ((unsigned)f2bf(a[1]*0.1f) << 16);
        o.y = (unsigned)f2bf(a[2]*0.1f) | ((unsigned)f2bf(a[3]*0.1f) << 16);
        o.z = (unsigned)f2bf(a[4]*0.1f) | ((unsigned)f2bf(a[5]*0.1f) << 16);
        o.w = (unsigned)f2bf(a[6]*0.1f) | ((unsigned)f2bf(a[7]*0.1f) << 16);
        *(uint4*)((unsigned short*)&X2[arow * 264 + acg * 8]) = o;
    }

    // ---- prologue: stage A(hop0 = hbf) + B(chunk 0) ---------------------------
    {
        uint4 va = *(const uint4*)(((const unsigned short*)hbf) + (m0 + arow) * 256 + acg * 8);
        *(uint4*)((unsigned short*)&Al[arow * 264 + acg * 8]) = va;
        uint4 v0 = *(const uint4*)(Wt + bn * 256 + bk);
        uint4 v1 = *(const uint4*)(Wt + bn * 256 + bk + 8);
        *(uint4*)(&Bl[0][bn * 72 + bk]) = v0;
        *(uint4*)(&Bl[0][bn * 72 + bk + 8]) = v1;
    }
    __syncthreads();

    f4v acc[2];
    acc[0] = (f4v){0.f, 0.f, 0.f, 0.f};
    acc[1] = (f4v){0.f, 0.f, 0.f, 0.f};

#pragma unroll
    for (int kc = 0; kc < 12; kc++) {
        const int cur = kc & 1;
        // 1. issue next-chunk B loads (latency hides under MFMA below)
        uint4 v0, v1;
        if (kc + 1 < 12) {
            const unsigned short* bsrc = Wt + ((kc + 1) >> 2) * 65536 + ((kc + 1) & 3) * 64;
            v0 = *(const uint4*)(bsrc + bn * 256 + bk);
            v1 = *(const uint4*)(bsrc + bn * 256 + bk + 8);
        }
        // 1b. at hop0->hop1 boundary, issue A(x1) loads early too
        uint4 va;
        if (kc == 3)
            va = *(const uint4*)(x1 + (m0 + arow) * 256 + acg * 8);
        // 2. MFMA on current chunk
        {
            const short* Abase = (kc < 8) ? Al : X2;
            int kl = (kc & 3) * 64;
#pragma unroll
            for (int ks = 0; ks < 2; ks++) {
                s8v a = *(const s8v*)(&Abase[(rt * 16 + l15) * 264 + kl + ks * 32 + quad * 8]);
#pragma unroll
                for (int f = 0; f < 2; f++) {
                    int n = (cfg * 2 + f) * 16 + l15;
                    s8v b = *(const s8v*)(&Bl[cur][n * 72 + ks * 32 + quad * 8]);
                    acc[f] = __builtin_amdgcn_mfma_f32_16x16x32_bf16(a, b, acc[f], 0, 0, 0);
                }
            }
        }
        // 3. write next-chunk B into the other buffer
        if (kc + 1 < 12) {
            *(uint4*)(&Bl[cur ^ 1][bn * 72 + bk]) = v0;
            *(uint4*)(&Bl[cur ^ 1][bn * 72 + bk + 8]) = v1;
        }
        __syncthreads();
        // 4. A restage (hop1 = x1) after hop0 reads complete
        if (kc == 3) {
            *(uint4*)((unsigned short*)&Al[arow * 264 + acg * 8]) = va;
            __syncthreads();
        }
    }

    // ---- epilogue: Euler update + readout partials ---------------------------
    float py[4][3] = {};
#pragma unroll
    for (int f = 0; f < 2; f++) {
        int col = (cfg * 2 + f) * 16 + l15;
        float cbv = cbl[col];
        float rw0 = rwl[col * 3], rw1 = rwl[col * 3 + 1], rw2 = rwl[col * 3 + 2];
#pragma unroll
        for (int r = 0; r < 4; r++) {
            int grow = m0 + rt * 16 + quad * 4 + r;
            float cval = acc[f][r] + cbv;
            float hn = hdo[grow * 256 + col] + EPSC * tanhf(cval);
            hdo[grow * 256 + col] = hn;
            hbf[grow * 256 + col] = f2bf(hn);
            py[r][0] += hn * rw0; py[r][1] += hn * rw1; py[r][2] += hn * rw2;
        }
    }
    for (int off = 1; off < 16; off <<= 1)
        for (int r = 0; r < 4; r++)
            for (int j = 0; j < 3; j++)
                py[r][j] += __shfl_xor(py[r][j], off, 64);
    if (l15 == 0)
        for (int r = 0; r < 4; r++)
            for (int j = 0; j < 3; j++)
                yred[w][quad][r][j] = py[r][j];
    __syncthreads();
    if (w == 0 && l15 == 0) {
        for (int rt2 = 0; rt2 < 2; rt2++) {
            for (int r = 0; r < 4; r++) {
                int grow = m0 + rt2 * 16 + quad * 4 + r;
                for (int j = 0; j < 3; j++) {
                    float yv = rb[j];
                    for (int ww = rt2 * 8; ww < rt2 * 8 + 8; ww++)
                        yv += yred[ww][quad][r][j];
                    yout[grow * 3 + j] = yv;
                    if (yfin) yfin[grow * 3 + j] = yv;
                }
            }
        }
    }
}

extern "C" void kernel_launch(void* const* d_in, const int* in_sizes, int n_in,
                              void* d_out, int out_size, void* d_ws, size_t ws_size,
                              hipStream_t stream) {
    const float* lm = (const float*)d_in[0];
    const float* ew = (const float*)d_in[1];
    const float* eb = (const float*)d_in[2];
    const float* rw = (const float*)d_in[3];
    const float* rb = (const float*)d_in[4];
    const float* cw = (const float*)d_in[5];
    const float* cb = (const float*)d_in[6];

    float* out = (float*)d_out;
    float* y_out = out;
    float* h_out = out + 24576;
    float* x_out = out + 24576 + 2097152;
    float* lp_out = x_out + 24576;

    char* ws = (char*)d_ws;
    int* nbr = (int*)ws;                       ws += NN * KNN * sizeof(int);
    float4* pos4 = (float4*)ws;                ws += NN * sizeof(float4);
    char* uni = ws;
    unsigned short* hbf = (unsigned short*)uni;
    unsigned short* x1  = hbf + NN * DH;
    unsigned short* Wt  = x1 + NN * DH;

    prep_pos<<<NN / 256, 256, 0, stream>>>(lm, pos4);
    knn_wave<<<NN / QPB, 1024, 0, stream>>>(lm, pos4, nbr);
    prep_wt<<<768, 256, 0, stream>>>(cw, Wt);
    emb_kernel<<<NN, 256, 0, stream>>>(lm, ew, eb, rw, rb, h_out, hbf, x_out);
    for (int t = 0; t < TSTEPS; t++) {
        agg_kernel<<<NN / 4, 256, 0, stream>>>(hbf, x1, nbr);
        gemm_step<<<NN / 32, 1024, 0, stream>>>(hbf, x1, nbr, Wt, cb, rw, rb, h_out,
                                                lp_out + t * 24576,
                                                (t == TSTEPS - 1) ? y_out : nullptr);
    }
}

// Round 9
// 380.085 us; speedup vs baseline: 2.1421x; 1.0493x over previous
//
#include <hip/hip_runtime.h>
#include <float.h>
#include <math.h>

#define NN 8192
#define DH 256
#define KNN 10
#define TSTEPS 10
#define EPSC 0.1f
#define CTILE 1024          // candidates staged in LDS per tile
#define QPB 16              // queries per block (16 waves of 64)

typedef short s8v __attribute__((ext_vector_type(8)));
typedef float f4v __attribute__((ext_vector_type(4)));

__device__ __forceinline__ float bf2f(unsigned short u) {
    union { unsigned u; float f; } c; c.u = ((unsigned)u) << 16; return c.f;
}
__device__ __forceinline__ unsigned short f2bf(float f) {
    union { float f; unsigned u; } c; c.f = f;
    unsigned r = c.u + 0x7FFF + ((c.u >> 16) & 1);
    return (unsigned short)(r >> 16);
}

// -------- conv_ws [3][256][256] (k,n) -> FRAGMENT-MAJOR bf16 Wt ---------------
// Layout: frag = (kc*2+ks)*16 + nb  (kc in 0..11 = K-chunk of 64, ks in 0..1,
// nb = n-block of 16). Within a fragment: lane 0..63 (quad=lane>>4, l15=lane&15)
// holds 8 shorts at k = kc*64+ks*32+quad*8+i8, n = nb*16+l15 — exactly the
// MFMA B operand. A wave's B load = 1KB contiguous (fully coalesced), so B
// needs NO LDS staging (R5's direct-B failed on 512B-stride scatter; this is
// dense).
__global__ void prep_wt(const float* __restrict__ W, unsigned short* __restrict__ Wt) {
    int e = blockIdx.x * 256 + threadIdx.x;     // 768*256 = 196608
    int i8 = e & 7, lane = (e >> 3) & 63, nb = (e >> 9) & 15;
    int ks = (e >> 13) & 1, kc2 = (e >> 14) & 3, g = e >> 16;
    int quad = lane >> 4, l15 = lane & 15;
    int k = kc2 * 64 + ks * 32 + quad * 8 + i8;
    int n = nb * 16 + l15;
    Wt[e] = f2bf(W[g * 65536 + k * 256 + n]);
}

// ---------------- pos4[j] = {x, y, z, |p|^2} ----------------------------------
__global__ void prep_pos(const float* __restrict__ pos, float4* __restrict__ pos4) {
    int j = blockIdx.x * 256 + threadIdx.x;
    float x = pos[j * 3], y = pos[j * 3 + 1], z = pos[j * 3 + 2];
    float4 v; v.x = x; v.y = y; v.z = z; v.w = x * x + y * y + z * z;
    pos4[j] = v;
}

// ---------------- kNN: 1 wave/query, 16 queries/block, DPP-insert pops --------
// Measured 54.7us (R7/R8). Kept as-is.
__launch_bounds__(1024)
__global__ void knn_wave(const float* __restrict__ pos, const float4* __restrict__ pos4,
                         int* __restrict__ nbr) {
    __shared__ float4 cand[CTILE];
    int tid = threadIdx.x;
    int wv = tid >> 6, lane = tid & 63;
    int i = blockIdx.x * QPB + wv;               // query for this wave
    float xi = pos[i * 3], yi = pos[i * 3 + 1], zi = pos[i * 3 + 2];
    float sqi = xi * xi + yi * yi + zi * zi;
    int igrp = i & ~63;                          // the only 64-group containing i

    float b  = FLT_MAX;                          // rank 'lane' distance
    int   ib = -1;                               // rank 'lane' index
    float thr = FLT_MAX;                         // 10th best (b at lane 9)

    for (int tile = 0; tile < NN / CTILE; ++tile) {
        __syncthreads();
        cand[tid] = pos4[tile * CTILE + tid];    // 1024 threads, 1 float4 each
        __syncthreads();
#pragma unroll 4
        for (int u = 0; u < CTILE / 64; ++u) {
            int jgrp = tile * CTILE + u * 64;
            float4 c = cand[u * 64 + lane];
            int j = jgrp + lane;
            float m = c.x * xi + c.y * yi + c.z * zi;
            float d = (sqi + c.w) - 2.0f * m;
            if (jgrp == igrp) {                  // wave-uniform branch
                if (j == i) d = FLT_MAX;         // self-exclusion, one batch only
            }
            unsigned long long mask = __ballot(d < thr);
            while (mask) {
                int l = __ffsll((unsigned long long)mask) - 1;
                mask &= mask - 1;
                float dc = __int_as_float(__builtin_amdgcn_readlane(__float_as_int(d), l));
                if (dc < thr) {                  // recheck vs updated threshold
                    int jc = __builtin_amdgcn_readlane(j, l);
                    // shift-down neighbors via DPP row_shr:1 (lane r <- r-1)
                    float bp = __int_as_float(__builtin_amdgcn_update_dpp(
                        0, __float_as_int(b), 0x111, 0xF, 0xF, true));
                    int ip = __builtin_amdgcn_update_dpp(0, ib, 0x111, 0xF, 0xF, true);
                    bool c0 = dc < b;                    // insert at/below my rank
                    bool cp = (lane != 0) && (dc < bp);  // insert strictly below
                    b  = c0 ? (cp ? bp : dc) : b;
                    ib = c0 ? (cp ? ip : jc) : ib;
                    thr = __int_as_float(__builtin_amdgcn_readlane(__float_as_int(b), 9));
                }
            }
        }
    }
    if (lane < KNN) nbr[i * KNN + lane] = ib;    // rank r already in lane r
}

// ---------------- h = lm@emb_w + emb_b ; x = h@rw + rb ------------------------
__global__ void emb_kernel(const float* __restrict__ lm, const float* __restrict__ ew,
                           const float* __restrict__ eb, const float* __restrict__ rw,
                           const float* __restrict__ rb,
                           float* __restrict__ hdo, unsigned short* __restrict__ hbf,
                           float* __restrict__ xout) {
    __shared__ float s0[4], s1[4], s2[4];
    int i = blockIdx.x, d = threadIdx.x;
    float a0 = lm[i * 3], a1 = lm[i * 3 + 1], a2 = lm[i * 3 + 2];
    float h = eb[d] + a0 * ew[d] + a1 * ew[256 + d] + a2 * ew[512 + d];
    hdo[i * 256 + d] = h;
    hbf[i * 256 + d] = f2bf(h);
    float p0 = h * rw[d * 3], p1 = h * rw[d * 3 + 1], p2 = h * rw[d * 3 + 2];
    for (int off = 32; off; off >>= 1) {
        p0 += __shfl_down(p0, off, 64);
        p1 += __shfl_down(p1, off, 64);
        p2 += __shfl_down(p2, off, 64);
    }
    int lane = d & 63, wid = d >> 6;
    if (lane == 0) { s0[wid] = p0; s1[wid] = p1; s2[wid] = p2; }
    __syncthreads();
    if (d == 0) {
        xout[i * 3 + 0] = s0[0] + s0[1] + s0[2] + s0[3] + rb[0];
        xout[i * 3 + 1] = s1[0] + s1[1] + s1[2] + s1[3] + rb[1];
        xout[i * 3 + 2] = s2[0] + s2[1] + s2[2] + s2[3] + rb[2];
    }
}

// ---------------- hop-1: x1[i] = 0.1 * sum_{j in nbr(i)} hbf[j] ---------------
// 8 nodes/block, 32 lanes/node, 16B/lane. All 10 index loads then all 10 row
// loads issued as a batch (no load->add serial chain).
__global__ void agg_kernel(const unsigned short* __restrict__ src,
                           unsigned short* __restrict__ dst,
                           const int* __restrict__ nbr) {
    int tid = threadIdx.x;
    int slot = tid >> 5, l32 = tid & 31;
    int node = blockIdx.x * 8 + slot;
    int d0 = l32 * 8;
    const int* nb = nbr + node * KNN;
    int j[KNN];
#pragma unroll
    for (int q = 0; q < KNN; q++) j[q] = nb[q];
    uint4 v[KNN];
#pragma unroll
    for (int q = 0; q < KNN; q++) v[q] = *(const uint4*)(src + j[q] * 256 + d0);
    float a[8];
#pragma unroll
    for (int e = 0; e < 8; e++) a[e] = 0.f;
#pragma unroll
    for (int q = 0; q < KNN; q++) {
        a[0] += bf2f((unsigned short)(v[q].x & 0xffff));
        a[1] += bf2f((unsigned short)(v[q].x >> 16));
        a[2] += bf2f((unsigned short)(v[q].y & 0xffff));
        a[3] += bf2f((unsigned short)(v[q].y >> 16));
        a[4] += bf2f((unsigned short)(v[q].z & 0xffff));
        a[5] += bf2f((unsigned short)(v[q].z >> 16));
        a[6] += bf2f((unsigned short)(v[q].w & 0xffff));
        a[7] += bf2f((unsigned short)(v[q].w >> 16));
    }
    uint4 o;
    o.x = (unsigned)f2bf(a[0]*0.1f) | ((unsigned)f2bf(a[1]*0.1f) << 16);
    o.y = (unsigned)f2bf(a[2]*0.1f) | ((unsigned)f2bf(a[3]*0.1f) << 16);
    o.z = (unsigned)f2bf(a[4]*0.1f) | ((unsigned)f2bf(a[5]*0.1f) << 16);
    o.w = (unsigned)f2bf(a[6]*0.1f) | ((unsigned)f2bf(a[7]*0.1f) << 16);
    *(uint4*)(dst + node * 256 + d0) = o;
}

// ------- fused: hop-2 gather + BARRIER-FREE-K GEMM + Euler + readout ----------
// M16 x N256, 512 threads (8 waves), grid 512 = 2 blocks/CU. B comes straight
// from fragment-major Wt (coalesced 1KB wave loads, no LDS, no staging
// barriers). A staged once: Ah(hbf) + A1(x1) + X2(gather) -> ONE barrier, then
// 12 K-chunks with zero barriers (compiler free to pipeline all 48 B loads).
// K order 0..767 ascending per output => bit-identical accumulation.
__launch_bounds__(512, 4)
__global__ void gemm_step(unsigned short* hbf,
                          const unsigned short* __restrict__ x1,
                          const int* __restrict__ nbr,
                          const unsigned short* __restrict__ Wt,
                          const float* __restrict__ cb,
                          const float* __restrict__ rw, const float* __restrict__ rb,
                          float* hdo, float* __restrict__ yout, float* yfin) {
    __shared__ __align__(16) short Ah[16 * 264];
    __shared__ __align__(16) short A1[16 * 264];
    __shared__ __align__(16) short X2[16 * 264];
    __shared__ float rwl[768];
    __shared__ float cbl[256];
    __shared__ float yred[8][4][4][3];     // [wave][quad][r][xyz]

    int tid = threadIdx.x;
    int m0 = blockIdx.x * 16;
    for (int idx = tid; idx < 768; idx += 512) rwl[idx] = rw[idx];
    if (tid < 256) cbl[tid] = cb[tid];

    int w = tid >> 6, lane = tid & 63;
    int quad = lane >> 4, l15 = lane & 15;
    int row = tid >> 5, cg = tid & 31;            // stage coords: 16 rows x 32 thr

    // ---- stage A for hop0 (hbf) and hop1 (x1) --------------------------------
    {
        uint4 va = *(const uint4*)(((const unsigned short*)hbf) + (m0 + row) * 256 + cg * 8);
        *(uint4*)((unsigned short*)&Ah[row * 264 + cg * 8]) = va;
        uint4 vb = *(const uint4*)(x1 + (m0 + row) * 256 + cg * 8);
        *(uint4*)((unsigned short*)&A1[row * 264 + cg * 8]) = vb;
    }
    // ---- hop-2 gather: X2[row][:] = bf16(0.1 * sum x1[nbr[row]]) -------------
    {
        const int* nb = nbr + (m0 + row) * KNN;
        int j[KNN];
#pragma unroll
        for (int q = 0; q < KNN; q++) j[q] = nb[q];
        float a[8];
#pragma unroll
        for (int e = 0; e < 8; e++) a[e] = 0.f;
#pragma unroll
        for (int q = 0; q < KNN; q++) {
            uint4 v = *(const uint4*)(x1 + j[q] * 256 + cg * 8);
            a[0] += bf2f((unsigned short)(v.x & 0xffff));
            a[1] += bf2f((unsigned short)(v.x >> 16));
            a[2] += bf2f((unsigned short)(v.y & 0xffff));
            a[3] += bf2f((unsigned short)(v.y >> 16));
            a[4] += bf2f((unsigned short)(v.z & 0xffff));
            a[5] += bf2f((unsigned short)(v.z >> 16));
            a[6] += bf2f((unsigned short)(v.w & 0xffff));
            a[7] += bf2f((unsigned short)(v.w >> 16));
        }
        uint4 o;
        o.x = (unsigned)f2bf(a[0]*0.1f) | ((unsigned)f2bf(a[1]*0.1f) << 16);
        o.y = (unsigned)f2bf(a[2]*0.1f) | ((unsigned)f2bf(a[3]*0.1f) << 16);
        o.z = (unsigned)f2bf(a[4]*0.1f) | ((unsigned)f2bf(a[5]*0.1f) << 16);
        o.w = (unsigned)f2bf(a[6]*0.1f) | ((unsigned)f2bf(a[7]*0.1f) << 16);
        *(uint4*)((unsigned short*)&X2[row * 264 + cg * 8]) = o;
    }
    __syncthreads();      // A buffers ready; K-loop is barrier-free from here

    f4v acc[2];
    acc[0] = (f4v){0.f, 0.f, 0.f, 0.f};
    acc[1] = (f4v){0.f, 0.f, 0.f, 0.f};

#pragma unroll
    for (int kc = 0; kc < 12; kc++) {
        const short* Ab = (kc < 4) ? Ah : (kc < 8) ? A1 : X2;
        int kl = (kc & 3) * 64;
#pragma unroll
        for (int ks = 0; ks < 2; ks++) {
            s8v a = *(const s8v*)(&Ab[l15 * 264 + kl + ks * 32 + quad * 8]);
#pragma unroll
            for (int f = 0; f < 2; f++) {
                // fragment-major B: one coalesced 1KB wave load
                s8v b = *(const s8v*)(Wt + ((kc * 2 + ks) * 16 + (w * 2 + f)) * 512 + lane * 8);
                acc[f] = __builtin_amdgcn_mfma_f32_16x16x32_bf16(a, b, acc[f], 0, 0, 0);
            }
        }
    }

    // ---- epilogue: Euler update + readout partials ---------------------------
    float py[4][3] = {};
#pragma unroll
    for (int f = 0; f < 2; f++) {
        int col = w * 32 + f * 16 + l15;
        float cbv = cbl[col];
        float rw0 = rwl[col * 3], rw1 = rwl[col * 3 + 1], rw2 = rwl[col * 3 + 2];
#pragma unroll
        for (int r = 0; r < 4; r++) {
            int grow = m0 + quad * 4 + r;
            float cval = acc[f][r] + cbv;
            float hn = hdo[grow * 256 + col] + EPSC * tanhf(cval);
            hdo[grow * 256 + col] = hn;
            hbf[grow * 256 + col] = f2bf(hn);
            py[r][0] += hn * rw0; py[r][1] += hn * rw1; py[r][2] += hn * rw2;
        }
    }
    for (int off = 1; off < 16; off <<= 1)
        for (int r = 0; r < 4; r++)
            for (int j = 0; j < 3; j++)
                py[r][j] += __shfl_xor(py[r][j], off, 64);
    if (l15 == 0)
        for (int r = 0; r < 4; r++)
            for (int j = 0; j < 3; j++)
                yred[w][quad][r][j] = py[r][j];
    __syncthreads();
    if (w == 0 && l15 == 0) {
        for (int r = 0; r < 4; r++) {
            int grow = m0 + quad * 4 + r;
            for (int j = 0; j < 3; j++) {
                float yv = rb[j];
                for (int ww = 0; ww < 8; ww++) yv += yred[ww][quad][r][j];
                yout[grow * 3 + j] = yv;
                if (yfin) yfin[grow * 3 + j] = yv;
            }
        }
    }
}

extern "C" void kernel_launch(void* const* d_in, const int* in_sizes, int n_in,
                              void* d_out, int out_size, void* d_ws, size_t ws_size,
                              hipStream_t stream) {
    const float* lm = (const float*)d_in[0];
    const float* ew = (const float*)d_in[1];
    const float* eb = (const float*)d_in[2];
    const float* rw = (const float*)d_in[3];
    const float* rb = (const float*)d_in[4];
    const float* cw = (const float*)d_in[5];
    const float* cb = (const float*)d_in[6];

    float* out = (float*)d_out;
    float* y_out = out;
    float* h_out = out + 24576;
    float* x_out = out + 24576 + 2097152;
    float* lp_out = x_out + 24576;

    char* ws = (char*)d_ws;
    int* nbr = (int*)ws;                       ws += NN * KNN * sizeof(int);
    float4* pos4 = (float4*)ws;                ws += NN * sizeof(float4);
    char* uni = ws;
    unsigned short* hbf = (unsigned short*)uni;
    unsigned short* x1  = hbf + NN * DH;
    unsigned short* Wt  = x1 + NN * DH;

    prep_pos<<<NN / 256, 256, 0, stream>>>(lm, pos4);
    knn_wave<<<NN / QPB, 1024, 0, stream>>>(lm, pos4, nbr);
    prep_wt<<<768, 256, 0, stream>>>(cw, Wt);
    emb_kernel<<<NN, 256, 0, stream>>>(lm, ew, eb, rw, rb, h_out, hbf, x_out);
    for (int t = 0; t < TSTEPS; t++) {
        agg_kernel<<<NN / 8, 256, 0, stream>>>(hbf, x1, nbr);
        gemm_step<<<NN / 16, 512, 0, stream>>>(hbf, x1, nbr, Wt, cb, rw, rb, h_out,
                                               lp_out + t * 24576,
                                               (t == TSTEPS - 1) ? y_out : nullptr);
    }
}